// Round 11
// baseline (37.823 us; speedup 1.0000x reference)
//
#include <hip/hip_runtime.h>
#include <hip/hip_fp16.h>

#define CUTN 128
#define CUT_SIZE 224
#define IMG_H 1024
#define IMG_W 1024
#define PAD 256          // IMG_H / 4
#define SIDE 1536        // IMG_H + 2*PAD
#define PX_PER_CUT (CUT_SIZE * CUT_SIZE)       // 50176
#define HALF_PX (PX_PER_CUT / 2)               // 25088 = 112 rows
#define BLOCKS_PER_CUT (HALF_PX / 256)         // 98
#define PLANE_PX (IMG_H * IMG_W)

// f32 -> fp16 image conversion, 4 px/thread, coalesced.
__global__ __launch_bounds__(256) void convert_kernel(
    const float* __restrict__ img, __half* __restrict__ dst)
{
    const int i = blockIdx.x * 256 + threadIdx.x;    // group of 4 px
    const int total4 = 3 * PLANE_PX / 4;             // 786432
    if (i >= total4) return;
    float4 v;
    __builtin_memcpy(&v, img + 4 * (size_t)i, 16);
    const __half2 a = __floats2half2_rn(v.x, v.y);
    const __half2 b = __floats2half2_rn(v.z, v.w);
    uint2 o;
    o.x = __builtin_bit_cast(unsigned int, a);
    o.y = __builtin_bit_cast(unsigned int, b);
    __builtin_memcpy(dst + 4 * (size_t)i, &o, 8);
}

// Round-9/10 structure (XCD-band remap, ballot dedupe, 2 px/thread, fp16
// image) + weight-folded branchless taps + 32-bit hot-path addressing.
template<bool HALFP>
__global__ __launch_bounds__(256) void make_cutouts_kernel(
    const float* __restrict__ img,      // (3, 1024, 1024) f32
    const __half* __restrict__ himg,    // (3, 1024, 1024) fp16 (if HALFP)
    const int* __restrict__ sizes_y,
    const int* __restrict__ sizes_x,
    const int* __restrict__ offs_y,
    const int* __restrict__ offs_x,
    float* __restrict__ out)            // (128, 3, 224, 224)
{
    const int bid = blockIdx.x;
    const int k = bid & 7;               // XCD id under round-robin dispatch
    const int j = bid >> 3;              // 0..1567 local index within XCD

    int cut, blk;
    if (j < 1536) {
        cut = j / 12;                    // cut-major: 12 blocks per cut
        blk = k * 12 + (j - cut * 12);   // vertical chunk k of this cut
    } else {
        const int e = j - 1536;          // 0..31: leftover blocks
        cut = (k >> 1) + (e << 2);       // cuts m ≡ k>>1 (mod 4)
        blk = 96 + (k & 1);
    }

    const int lane = (int)(threadIdx.x & 63);

    const int sy = sizes_y[cut], sx = sizes_x[cut];
    const int oy = offs_y[cut],  ox = offs_x[cut];

    // ---- ballot dedupe: lane l checks cuts l and l+64 ----
    const bool eq_lo = (sizes_y[lane]      == sy) & (sizes_x[lane]      == sx) &
                       (offs_y[lane]       == oy) & (offs_x[lane]       == ox);
    const bool eq_hi = (sizes_y[lane + 64] == sy) & (sizes_x[lane + 64] == sx) &
                       (offs_y[lane + 64]  == oy) & (offs_x[lane + 64]  == ox);
    const unsigned long long mlo = __ballot(eq_lo);
    const unsigned long long mhi = __ballot(eq_hi);
    const int canon = mlo ? (__ffsll(mlo) - 1) : (__ffsll(mhi) + 63);
    if (canon != cut) return;            // an earlier identical cutout owns this

    const float syf = (float)sy, sxf = (float)sx;
    const float oyf = (float)oy, oxf = (float)ox;

    const int p  = blk * 256 + (int)threadIdx.x;     // 0..25087
    const int y  = p / CUT_SIZE;                     // 0..111
    const int x  = p - y * CUT_SIZE;

    // ---- x-side (shared by both pixels); folded into coefficients ----
    const float gx = ((float)x + 0.5f) / (float)CUT_SIZE;
    const float xs = fminf(fmaxf(oxf + gx * sxf - 0.5f, 0.0f), (float)(SIDE - 1));
    const int   x0 = (int)floorf(xs);
    const float wx = xs - (float)x0;
    const int  xx0 = x0 - PAD;
    const int  xx1 = min(x0 + 1, SIDE - 1) - PAD;
    const bool vx0 = (unsigned)xx0 < (unsigned)IMG_W;
    const bool vx1 = (unsigned)xx1 < (unsigned)IMG_W;
    const int   ax = min(max(xx0, 0), IMG_W - 2);    // clamped pair base
    const bool  s0 = (xx0 != ax);    // p00 comes from .y instead of .x
    const bool  s1 = (xx1 == ax);    // p01 comes from .x instead of .y

    // x-side coefficient of pair element .x and .y (validity+clamp folded)
    const float cx_x = ((vx0 && !s0) ? (1.0f - wx) : 0.0f)
                     + ((vx1 &&  s1) ? wx          : 0.0f);
    const float cx_y = ((vx0 &&  s0) ? (1.0f - wx) : 0.0f)
                     + ((vx1 && !s1) ? wx          : 0.0f);

    float vout[2][3];

    #pragma unroll
    for (int h = 0; h < 2; ++h) {
        const int yy = y + h * 112;

        const float gy = ((float)yy + 0.5f) / (float)CUT_SIZE;
        const float ysf = fminf(fmaxf(oyf + gy * syf - 0.5f, 0.0f), (float)(SIDE - 1));
        const int   y0 = (int)floorf(ysf);
        const float wy = ysf - (float)y0;
        const int  yy0 = y0 - PAD;
        const int  yy1 = min(y0 + 1, SIDE - 1) - PAD;
        const float wyl0 = ((unsigned)yy0 < (unsigned)IMG_H) ? (1.0f - wy) : 0.0f;
        const float wyl1 = ((unsigned)yy1 < (unsigned)IMG_H) ? wy          : 0.0f;
        const int   r0 = min(max(yy0, 0), IMG_H - 1);
        const int   r1 = min(max(yy1, 0), IMG_H - 1);

        // 4 final coefficients, shared by the 3 channels
        const float cax = wyl0 * cx_x;
        const float cay = wyl0 * cx_y;
        const float cbx = wyl1 * cx_x;
        const float cby = wyl1 * cx_y;

        const int o0 = r0 * IMG_W + ax;              // 32-bit offsets
        const int o1 = r1 * IMG_W + ax;

        #pragma unroll
        for (int c = 0; c < 3; ++c) {
            float2 a, b;
            if constexpr (HALFP) {
                const __half* hplane = himg + c * PLANE_PX;
                unsigned int ua, ub;
                __builtin_memcpy(&ua, hplane + o0, 4);   // halves {ax, ax+1}
                __builtin_memcpy(&ub, hplane + o1, 4);
                a = __half22float2(__builtin_bit_cast(__half2, ua));
                b = __half22float2(__builtin_bit_cast(__half2, ub));
            } else {
                const float* plane = img + c * PLANE_PX;
                __builtin_memcpy(&a, plane + o0, 8);
                __builtin_memcpy(&b, plane + o1, 8);
            }
            vout[h][c] = a.x * cax + a.y * cay + b.x * cbx + b.y * cby;
        }
    }

    // ---- write own cutout and all duplicates (mask uniform per block) ----
    unsigned long long lo = mlo, hi = mhi;
    while (lo) {
        const int d = __ffsll(lo) - 1; lo &= lo - 1;
        const int obase = (d * 3) * PX_PER_CUT + p;  // 32-bit out offsets
        #pragma unroll
        for (int h = 0; h < 2; ++h)
            #pragma unroll
            for (int c = 0; c < 3; ++c)
                __builtin_nontemporal_store(
                    vout[h][c], &out[obase + c * PX_PER_CUT + h * HALF_PX]);
    }
    while (hi) {
        const int d = __ffsll(hi) + 63; hi &= hi - 1;
        const int obase = (d * 3) * PX_PER_CUT + p;
        #pragma unroll
        for (int h = 0; h < 2; ++h)
            #pragma unroll
            for (int c = 0; c < 3; ++c)
                __builtin_nontemporal_store(
                    vout[h][c], &out[obase + c * PX_PER_CUT + h * HALF_PX]);
    }
}

extern "C" void kernel_launch(void* const* d_in, const int* in_sizes, int n_in,
                              void* d_out, int out_size, void* d_ws, size_t ws_size,
                              hipStream_t stream) {
    const float* img     = (const float*)d_in[0];
    const int*   sizes_y = (const int*)d_in[1];
    const int*   sizes_x = (const int*)d_in[2];
    const int*   offs_y  = (const int*)d_in[3];
    const int*   offs_x  = (const int*)d_in[4];
    float* out = (float*)d_out;

    const int grid = CUTN * BLOCKS_PER_CUT;   // 12544 blocks of 256
    const size_t hneed = (size_t)3 * PLANE_PX * sizeof(__half);   // 6 MB

    if (ws_size >= hneed) {
        __half* himg = (__half*)d_ws;
        const int cgrid = (3 * PLANE_PX / 4 + 255) / 256;   // 3072
        convert_kernel<<<cgrid, 256, 0, stream>>>(img, himg);
        make_cutouts_kernel<true><<<grid, 256, 0, stream>>>(
            img, himg, sizes_y, sizes_x, offs_y, offs_x, out);
    } else {
        make_cutouts_kernel<false><<<grid, 256, 0, stream>>>(
            img, nullptr, sizes_y, sizes_x, offs_y, offs_x, out);
    }
}